// Round 3
// baseline (655.980 us; speedup 1.0000x reference)
//
#include <hip/hip_runtime.h>
#include <hip/hip_bf16.h>
#include <stdint.h>
#include <stddef.h>

// Problem constants
#define Bn  2
#define Tn  2048
#define Cn  2048
#define Hn  16
#define HDn 128

// may_alias vector types for memory access (TBAA-safe); plain short8 for MFMA args
typedef short short8   __attribute__((ext_vector_type(8)));
typedef short short8_a __attribute__((ext_vector_type(8), may_alias));
typedef unsigned int u32x4_a __attribute__((ext_vector_type(4), may_alias));
typedef unsigned short u16x4_a __attribute__((ext_vector_type(4), may_alias));
typedef float f32x4 __attribute__((ext_vector_type(4)));

__device__ inline unsigned short f2b(float f) {
    union { float f; unsigned u; } v; v.f = f;
    unsigned r = v.u + 0x7fffu + ((v.u >> 16) & 1u);   // RNE
    return (unsigned short)(r >> 16);
}
// 4x fp32 bits -> 4x bf16 (RNE), operating on raw words
__device__ inline u16x4_a cvt4_f32_bf16(u32x4_a v) {
    u16x4_a h;
#pragma unroll
    for (int e = 0; e < 4; e++) {
        unsigned u = v[e];
        unsigned r = u + 0x7fffu + ((u >> 16) & 1u);
        h[e] = (unsigned short)(r >> 16);
    }
    return h;
}

// C[m,n] = sum_k A[m,k]*B[n,k] (+bias[n]).
// A: fp32 [M,K] (A_BF16=0) or bf16 [M,K] (A_BF16=1). B: fp32 [N,K]. Out: fp32 or bf16.
// Inputs converted to bf16 during staging; MFMA bf16; fp32 accumulate.
// 128x128 tile, BK=32, 256 threads = 4 waves, each wave 64x64 (4x4 MFMA 16x16 tiles)
template<int A_BF16, int OUT_F32, int HAS_BIAS>
__global__ __launch_bounds__(256, 2)
void gemm_kernel(const void* __restrict__ Av, const float* __restrict__ Bf,
                 const float* __restrict__ bias, void* __restrict__ Cv,
                 int M, int N, int K)
{
    // LDS row stride 40 elems (80 B) to break power-of-2 bank strides
    __shared__ __align__(16) unsigned short As[128 * 40];
    __shared__ __align__(16) unsigned short Bs[128 * 40];

    const int tid  = threadIdx.x;
    const int lane = tid & 63;
    const int wave = tid >> 6;
    const int quad = lane >> 4;
    const int l15  = lane & 15;
    const int tm = blockIdx.x * 128;
    const int tn = blockIdx.y * 128;
    const int wr = (wave >> 1) * 64;
    const int wc = (wave & 1) * 64;

    f32x4 acc[4][4];
#pragma unroll
    for (int i = 0; i < 4; i++)
#pragma unroll
        for (int j = 0; j < 4; j++) acc[i][j] = (f32x4){0.f, 0.f, 0.f, 0.f};

    u32x4_a apre[4], bpre[4];
    const int ksteps = K >> 5;

    // staging maps:
    //  bf16 source: r0 = tid>>2 (row), cg=(tid&3)*8 (8 elems); rows r0, r0+64
    //  fp32 source: idx = tid+rep*256 (rep<4); row=idx>>3, c4=(idx&7)*4 (4 elems)
    const int r0 = tid >> 2;
    const int cg = (tid & 3) * 8;

    auto loadA = [&](int k0) {
        if (A_BF16) {
            const unsigned short* Ab = (const unsigned short*)Av;
            apre[0] = *(const u32x4_a*)(Ab + (size_t)(tm + r0) * K + k0 + cg);
            apre[1] = *(const u32x4_a*)(Ab + (size_t)(tm + r0 + 64) * K + k0 + cg);
        } else {
            const float* Af = (const float*)Av;
#pragma unroll
            for (int rep = 0; rep < 4; rep++) {
                const int idx = tid + rep * 256, row = idx >> 3, c4 = (idx & 7) * 4;
                apre[rep] = *(const u32x4_a*)(Af + (size_t)(tm + row) * K + k0 + c4);
            }
        }
    };
    auto loadB = [&](int k0) {
#pragma unroll
        for (int rep = 0; rep < 4; rep++) {
            const int idx = tid + rep * 256, row = idx >> 3, c4 = (idx & 7) * 4;
            bpre[rep] = *(const u32x4_a*)(Bf + (size_t)(tn + row) * K + k0 + c4);
        }
    };
    auto stage = [&]() {
        if (A_BF16) {
            *(u32x4_a*)&As[r0 * 40 + cg]        = apre[0];
            *(u32x4_a*)&As[(r0 + 64) * 40 + cg] = apre[1];
        } else {
#pragma unroll
            for (int rep = 0; rep < 4; rep++) {
                const int idx = tid + rep * 256, row = idx >> 3, c4 = (idx & 7) * 4;
                *(u16x4_a*)&As[row * 40 + c4] = cvt4_f32_bf16(apre[rep]);
            }
        }
#pragma unroll
        for (int rep = 0; rep < 4; rep++) {
            const int idx = tid + rep * 256, row = idx >> 3, c4 = (idx & 7) * 4;
            *(u16x4_a*)&Bs[row * 40 + c4] = cvt4_f32_bf16(bpre[rep]);
        }
    };

    loadA(0);
    loadB(0);

    for (int kt = 0; kt < ksteps; ++kt) {
        stage();
        __syncthreads();
        if (kt + 1 < ksteps) {
            const int k0 = (kt + 1) << 5;
            loadA(k0);
            loadB(k0);
        }
        short8 af[4], bf[4];
#pragma unroll
        for (int i = 0; i < 4; i++)
            af[i] = (short8)(*(const short8_a*)&As[(wr + i * 16 + l15) * 40 + quad * 8]);
#pragma unroll
        for (int j = 0; j < 4; j++)
            bf[j] = (short8)(*(const short8_a*)&Bs[(wc + j * 16 + l15) * 40 + quad * 8]);
#pragma unroll
        for (int i = 0; i < 4; i++)
#pragma unroll
            for (int j = 0; j < 4; j++)
                acc[i][j] = __builtin_amdgcn_mfma_f32_16x16x32_bf16(af[i], bf[j], acc[i][j], 0, 0, 0);
        __syncthreads();
    }

    // epilogue: D row = quad*4 + reg, col = lane&15 (verified C/D layout)
#pragma unroll
    for (int i = 0; i < 4; i++) {
        const int row = tm + wr + i * 16 + quad * 4;
#pragma unroll
        for (int j = 0; j < 4; j++) {
            const int col = tn + wc + j * 16 + l15;
            const float bv = HAS_BIAS ? bias[col] : 0.0f;
#pragma unroll
            for (int r = 0; r < 4; r++) {
                if (OUT_F32)
                    ((float*)Cv)[(size_t)(row + r) * N + col] = acc[i][j][r] + bv;
                else
                    ((unsigned short*)Cv)[(size_t)(row + r) * N + col] = f2b(acc[i][j][r] + bv);
            }
        }
    }
}

// Flash attention, causal. All tensors bf16.
// q    [B*T, C]  row stride 2048, head h at col h*128
// kv   [B*T, 2C] row stride 4096: k at col h*128, v at col 2048 + h*128
// outp [B*T, C]  — SAME buffer as q (per-block-safe overwrite)
// Block: 128 Q rows for one (b,h); 4 waves x 32 Q rows. K-tiles of 64 keys.
__global__ __launch_bounds__(256, 2)
void attn_kernel(const unsigned short* __restrict__ q,
                 const unsigned short* __restrict__ kv,
                 unsigned short* __restrict__ outp)
{
    __shared__ __align__(16) unsigned short Ks[64 * 136];   // [key][d], stride 136
    __shared__ __align__(16) unsigned short Vs[128 * 72];   // [d][key] transposed, stride 72
    __shared__ __align__(16) unsigned short Ps[4][32 * 72]; // per-wave P, stride 72

    const int qt   = blockIdx.x;          // q tile (16)
    const int bh   = blockIdx.y;          // b*H + h (32)
    const int b    = bh >> 4;
    const int h    = bh & 15;
    const int tid  = threadIdx.x;
    const int lane = tid & 63;
    const int wave = tid >> 6;
    const int quad = lane >> 4;
    const int l15  = lane & 15;

    // Q A-fragments in registers: rows qrow0..+32, A[m=lane&15][k=quad*8+j]
    short8 qf[2][4];
    const int qrow0 = qt * 128 + wave * 32;
#pragma unroll
    for (int i = 0; i < 2; i++)
#pragma unroll
        for (int kk = 0; kk < 4; kk++) {
            const unsigned short* p = q + (size_t)(b * Tn + qrow0 + i * 16 + l15) * Cn
                                      + h * HDn + kk * 32 + quad * 8;
            qf[i][kk] = (short8)(*(const short8_a*)p);
        }

    float m_i[2][4], l_i[2][4];
    f32x4 o_acc[2][8];
#pragma unroll
    for (int i = 0; i < 2; i++) {
#pragma unroll
        for (int r = 0; r < 4; r++) { m_i[i][r] = -1e30f; l_i[i][r] = 0.f; }
#pragma unroll
        for (int jd = 0; jd < 8; jd++) o_acc[i][jd] = (f32x4){0.f, 0.f, 0.f, 0.f};
    }

    const int ktiles = 2 * qt + 2;   // causal: keys up to qt*128+127
    for (int kt2 = 0; kt2 < ktiles; ++kt2) {
        const int kk0 = kt2 * 64;
        __syncthreads();
        // stage K natural, V transposed
#pragma unroll
        for (int rep = 0; rep < 4; ++rep) {
            const int idx  = tid + rep * 256;     // 0..1023
            const int krow = idx >> 4;            // 0..63
            const int dg   = (idx & 15) * 8;      // 0..120
            const unsigned short* kp = kv + (size_t)(b * Tn + kk0 + krow) * (2 * Cn)
                                       + h * HDn + dg;
            *(u32x4_a*)&Ks[krow * 136 + dg] = *(const u32x4_a*)kp;
            const unsigned short* vp = kv + (size_t)(b * Tn + kk0 + krow) * (2 * Cn)
                                       + Cn + h * HDn + dg;
            u32x4_a vv = *(const u32x4_a*)vp;
            const unsigned short* ve = (const unsigned short*)&vv;
#pragma unroll
            for (int e = 0; e < 8; e++) Vs[(dg + e) * 72 + krow] = ve[e];
        }
        __syncthreads();

        // S = Q K^T  (wave: 32 q-rows x 64 keys, 2x4 tiles, 4 k-steps over HD=128)
        f32x4 s[2][4];
#pragma unroll
        for (int i = 0; i < 2; i++)
#pragma unroll
            for (int j = 0; j < 4; j++) s[i][j] = (f32x4){0.f, 0.f, 0.f, 0.f};
#pragma unroll
        for (int kk = 0; kk < 4; ++kk) {
            short8 kf[4];
#pragma unroll
            for (int j = 0; j < 4; j++)
                kf[j] = (short8)(*(const short8_a*)&Ks[(j * 16 + l15) * 136 + kk * 32 + quad * 8]);
#pragma unroll
            for (int i = 0; i < 2; i++)
#pragma unroll
                for (int j = 0; j < 4; j++)
                    s[i][j] = __builtin_amdgcn_mfma_f32_16x16x32_bf16(qf[i][kk], kf[j], s[i][j], 0, 0, 0);
        }

        // online softmax: row = i*16+quad*4+r, col = j*16+l15
#pragma unroll
        for (int i = 0; i < 2; i++) {
#pragma unroll
            for (int r = 0; r < 4; r++) {
                const int qidx = qrow0 + i * 16 + quad * 4 + r;
                float mx = -1e30f;
#pragma unroll
                for (int j = 0; j < 4; j++) {
                    const int kidx = kk0 + j * 16 + l15;
                    float v = s[i][j][r] * 0.08838834764831845f;
                    v = (kidx <= qidx) ? v : -1e30f;
                    s[i][j][r] = v;
                    mx = fmaxf(mx, v);
                }
#pragma unroll
                for (int off = 1; off < 16; off <<= 1)
                    mx = fmaxf(mx, __shfl_xor(mx, off));
                const float mn = fmaxf(m_i[i][r], mx);
                const float al = __expf(fminf(m_i[i][r] - mn, 0.f));
                m_i[i][r] = mn;
                float rs = 0.f;
#pragma unroll
                for (int j = 0; j < 4; j++) {
                    const float p = __expf(fminf(s[i][j][r] - mn, 0.f));
                    s[i][j][r] = p;
                    rs += p;
                }
#pragma unroll
                for (int off = 1; off < 16; off <<= 1)
                    rs += __shfl_xor(rs, off);
                l_i[i][r] = l_i[i][r] * al + rs;
#pragma unroll
                for (int jd = 0; jd < 8; jd++) o_acc[i][jd][r] *= al;
                // P -> LDS (C-layout write; read back below in A-layout)
#pragma unroll
                for (int j = 0; j < 4; j++)
                    Ps[wave][(i * 16 + quad * 4 + r) * 72 + j * 16 + l15] = f2b(s[i][j][r]);
            }
        }
        __syncthreads();   // P writes visible

        // O += P V   (P: A-frag from Ps; V: B-frag from transposed Vs)
#pragma unroll
        for (int kk2 = 0; kk2 < 2; ++kk2) {
            short8 pf[2];
#pragma unroll
            for (int i = 0; i < 2; i++)
                pf[i] = (short8)(*(const short8_a*)&Ps[wave][(i * 16 + l15) * 72 + kk2 * 32 + quad * 8]);
#pragma unroll
            for (int jd = 0; jd < 8; jd++) {
                short8 vf = (short8)(*(const short8_a*)&Vs[(jd * 16 + l15) * 72 + kk2 * 32 + quad * 8]);
#pragma unroll
                for (int i = 0; i < 2; i++)
                    o_acc[i][jd] = __builtin_amdgcn_mfma_f32_16x16x32_bf16(pf[i], vf, o_acc[i][jd], 0, 0, 0);
            }
        }
    }

    // epilogue: out[b*T + t, h*128 + d] = o/l  (overwrites this block's own q — safe)
#pragma unroll
    for (int i = 0; i < 2; i++) {
#pragma unroll
        for (int r = 0; r < 4; r++) {
            const float inv = 1.0f / fmaxf(l_i[i][r], 1e-20f);
            const int trow = qrow0 + i * 16 + quad * 4 + r;
#pragma unroll
            for (int jd = 0; jd < 8; jd++) {
                const int col = h * HDn + jd * 16 + l15;
                outp[(size_t)(b * Tn + trow) * Cn + col] = f2b(o_acc[i][jd][r] * inv);
            }
        }
    }
}

extern "C" void kernel_launch(void* const* d_in, const int* in_sizes, int n_in,
                              void* d_out, int out_size, void* d_ws, size_t ws_size,
                              hipStream_t stream)
{
    const float* x      = (const float*)d_in[0]; // [B,T,C]  fp32
    const float* w_attn = (const float*)d_in[1]; // [3C,C]   fp32
    const float* w_proj = (const float*)d_in[2]; // [C,C]    fp32
    const float* b_proj = (const float*)d_in[3]; // [C]      fp32
    float* out = (float*)d_out;                  // [B,T,C]  fp32 (32 MiB)

    // Buffer plan:
    //   qbuf  = d_ws   [4096,2048] bf16 (16 MiB) — q, then attn output (same-block overwrite)
    //   kvbuf = d_out  [4096,4096] bf16 (32 MiB) — k|v, dead before proj GEMM writes fp32 out
    unsigned short* qbuf  = (unsigned short*)d_ws;
    unsigned short* kvbuf = (unsigned short*)d_out;

    // q  = x @ w_attn[0:2048]^T    : M=4096, N=2048, K=2048 (fp32 in, bf16 out)
    gemm_kernel<0, 0, 0><<<dim3(32, 16), 256, 0, stream>>>(x, w_attn, nullptr, qbuf,
                                                           Bn * Tn, Cn, Cn);
    // kv = x @ w_attn[2048:6144]^T : M=4096, N=4096, K=2048 (fp32 in, bf16 out)
    gemm_kernel<0, 0, 0><<<dim3(32, 32), 256, 0, stream>>>(x, w_attn + (size_t)Cn * Cn, nullptr,
                                                           kvbuf, Bn * Tn, 2 * Cn, Cn);
    // flash attention: q/kv bf16 -> att bf16 (over q)
    attn_kernel<<<dim3(Tn / 128, Bn * Hn), 256, 0, stream>>>(qbuf, kvbuf, qbuf);
    // out = att @ w_proj^T + b_proj : M=4096, N=2048, K=2048 (A bf16, B fp32, out fp32)
    gemm_kernel<1, 1, 1><<<dim3(32, 16), 256, 0, stream>>>(qbuf, w_proj, b_proj, out,
                                                           Bn * Tn, Cn, Cn);
}

// Round 4
// 551.251 us; speedup vs baseline: 1.1900x; 1.1900x over previous
//
#include <hip/hip_runtime.h>
#include <hip/hip_bf16.h>
#include <stdint.h>
#include <stddef.h>

// Problem constants
#define Bn  2
#define Tn  2048
#define Cn  2048
#define Hn  16
#define HDn 128

// may_alias vector types for memory access (TBAA-safe); plain short8 for MFMA args
typedef short short8   __attribute__((ext_vector_type(8)));
typedef short short8_a __attribute__((ext_vector_type(8), may_alias));
typedef unsigned int u32x4_a __attribute__((ext_vector_type(4), may_alias));
typedef unsigned short u16x4_a __attribute__((ext_vector_type(4), may_alias));
typedef float f32x4 __attribute__((ext_vector_type(4)));

__device__ inline unsigned short f2b(float f) {
    union { float f; unsigned u; } v; v.f = f;
    unsigned r = v.u + 0x7fffu + ((v.u >> 16) & 1u);   // RNE
    return (unsigned short)(r >> 16);
}
// 4x fp32 bits -> 4x bf16 (RNE), operating on raw words
__device__ inline u16x4_a cvt4_f32_bf16(u32x4_a v) {
    u16x4_a h;
#pragma unroll
    for (int e = 0; e < 4; e++) {
        unsigned u = v[e];
        unsigned r = u + 0x7fffu + ((u >> 16) & 1u);
        h[e] = (unsigned short)(r >> 16);
    }
    return h;
}

// C[m,n] = sum_k A[m,k]*B[n,k] (+bias[n]).
// A: fp32 [M,K] (A_BF16=0) or bf16 [M,K] (A_BF16=1). B: fp32 [N,K]. Out: fp32 or bf16.
// Inputs converted to bf16 during staging; MFMA bf16; fp32 accumulate.
// 128x128 tile, BK=32, 256 threads = 4 waves, each wave 64x64 (4x4 MFMA 16x16 tiles)
template<int A_BF16, int OUT_F32, int HAS_BIAS>
__global__ __launch_bounds__(256, 2)
void gemm_kernel(const void* __restrict__ Av, const float* __restrict__ Bf,
                 const float* __restrict__ bias, void* __restrict__ Cv,
                 int M, int N, int K)
{
    // LDS row stride 40 elems (80 B) to break power-of-2 bank strides
    __shared__ __align__(16) unsigned short As[128 * 40];
    __shared__ __align__(16) unsigned short Bs[128 * 40];

    const int tid  = threadIdx.x;
    const int lane = tid & 63;
    const int wave = tid >> 6;
    const int quad = lane >> 4;
    const int l15  = lane & 15;
    const int tm = blockIdx.x * 128;
    const int tn = blockIdx.y * 128;
    const int wr = (wave >> 1) * 64;
    const int wc = (wave & 1) * 64;

    f32x4 acc[4][4];
#pragma unroll
    for (int i = 0; i < 4; i++)
#pragma unroll
        for (int j = 0; j < 4; j++) acc[i][j] = (f32x4){0.f, 0.f, 0.f, 0.f};

    u32x4_a apre[4], bpre[4];
    const int ksteps = K >> 5;

    const int r0 = tid >> 2;
    const int cg = (tid & 3) * 8;

    auto loadA = [&](int k0) {
        if (A_BF16) {
            const unsigned short* Ab = (const unsigned short*)Av;
            apre[0] = *(const u32x4_a*)(Ab + (size_t)(tm + r0) * K + k0 + cg);
            apre[1] = *(const u32x4_a*)(Ab + (size_t)(tm + r0 + 64) * K + k0 + cg);
        } else {
            const float* Af = (const float*)Av;
#pragma unroll
            for (int rep = 0; rep < 4; rep++) {
                const int idx = tid + rep * 256, row = idx >> 3, c4 = (idx & 7) * 4;
                apre[rep] = *(const u32x4_a*)(Af + (size_t)(tm + row) * K + k0 + c4);
            }
        }
    };
    auto loadB = [&](int k0) {
#pragma unroll
        for (int rep = 0; rep < 4; rep++) {
            const int idx = tid + rep * 256, row = idx >> 3, c4 = (idx & 7) * 4;
            bpre[rep] = *(const u32x4_a*)(Bf + (size_t)(tn + row) * K + k0 + c4);
        }
    };
    auto stage = [&]() {
        if (A_BF16) {
            *(u32x4_a*)&As[r0 * 40 + cg]        = apre[0];
            *(u32x4_a*)&As[(r0 + 64) * 40 + cg] = apre[1];
        } else {
#pragma unroll
            for (int rep = 0; rep < 4; rep++) {
                const int idx = tid + rep * 256, row = idx >> 3, c4 = (idx & 7) * 4;
                *(u16x4_a*)&As[row * 40 + c4] = cvt4_f32_bf16(apre[rep]);
            }
        }
#pragma unroll
        for (int rep = 0; rep < 4; rep++) {
            const int idx = tid + rep * 256, row = idx >> 3, c4 = (idx & 7) * 4;
            *(u16x4_a*)&Bs[row * 40 + c4] = cvt4_f32_bf16(bpre[rep]);
        }
    };

    loadA(0);
    loadB(0);

    for (int kt = 0; kt < ksteps; ++kt) {
        stage();
        __syncthreads();
        if (kt + 1 < ksteps) {
            const int k0 = (kt + 1) << 5;
            loadA(k0);
            loadB(k0);
        }
        short8 af[4], bf[4];
#pragma unroll
        for (int i = 0; i < 4; i++)
            af[i] = (short8)(*(const short8_a*)&As[(wr + i * 16 + l15) * 40 + quad * 8]);
#pragma unroll
        for (int j = 0; j < 4; j++)
            bf[j] = (short8)(*(const short8_a*)&Bs[(wc + j * 16 + l15) * 40 + quad * 8]);
#pragma unroll
        for (int i = 0; i < 4; i++)
#pragma unroll
            for (int j = 0; j < 4; j++)
                acc[i][j] = __builtin_amdgcn_mfma_f32_16x16x32_bf16(af[i], bf[j], acc[i][j], 0, 0, 0);
        __syncthreads();
    }

    // epilogue: D row = quad*4 + reg, col = lane&15 (verified C/D layout)
#pragma unroll
    for (int i = 0; i < 4; i++) {
        const int row = tm + wr + i * 16 + quad * 4;
#pragma unroll
        for (int j = 0; j < 4; j++) {
            const int col = tn + wc + j * 16 + l15;
            const float bv = HAS_BIAS ? bias[col] : 0.0f;
#pragma unroll
            for (int r = 0; r < 4; r++) {
                if (OUT_F32)
                    ((float*)Cv)[(size_t)(row + r) * N + col] = acc[i][j][r] + bv;
                else
                    ((unsigned short*)Cv)[(size_t)(row + r) * N + col] = f2b(acc[i][j][r] + bv);
            }
        }
    }
}

// Flash attention, causal. All tensors bf16.
// q    [B*T, C]  row stride 2048, head h at col h*128
// kv   [B*T, 2C] row stride 4096: k at col h*128, v at col 2048 + h*128
// outp [B*T, C]  — SAME buffer as q (per-block-safe overwrite)
// Balanced pairing: block (qp, bh) processes q-tiles qp and 15-qp for head bh:
// (2*qp+2) + (32-2*qp) = 34 k-tile iters for every block. Grid 8x32 = 256 blocks.
// 4 waves x 32 Q rows per q-tile. K-tiles of 64 keys, register-prefetched.
// Vs XOR-swizzle: pcol = key ^ (((d>>3)&7)<<3) — 8-key blocks stay contiguous
// (b128 reads ok), scalar transpose-writes spread 2 banks -> 16 banks.
__global__ __launch_bounds__(256, 1)
void attn_kernel(const unsigned short* __restrict__ q,
                 const unsigned short* __restrict__ kv,
                 unsigned short* __restrict__ outp)
{
    __shared__ __align__(16) unsigned short Ks[64 * 136];   // [key][d], stride 136
    __shared__ __align__(16) unsigned short Vs[128 * 72];   // [d][pcol] swizzled, stride 72
    __shared__ __align__(16) unsigned short Ps[4][32 * 72]; // per-wave P, stride 72

    const int qp   = blockIdx.x;          // q pair index (0..7)
    const int bh   = blockIdx.y;          // b*H + h (32)
    const int b    = bh >> 4;
    const int h    = bh & 15;
    const int tid  = threadIdx.x;
    const int lane = tid & 63;
    const int wave = tid >> 6;
    const int quad = lane >> 4;
    const int l15  = lane & 15;

    for (int half = 0; half < 2; ++half) {
        const int qt = half ? (15 - qp) : qp;
        const int qrow0 = qt * 128 + wave * 32;

        // Q A-fragments in registers: rows qrow0..+32, A[m=lane&15][k=quad*8+j]
        short8 qf[2][4];
#pragma unroll
        for (int i = 0; i < 2; i++)
#pragma unroll
            for (int kk = 0; kk < 4; kk++) {
                const unsigned short* p = q + (size_t)(b * Tn + qrow0 + i * 16 + l15) * Cn
                                          + h * HDn + kk * 32 + quad * 8;
                qf[i][kk] = (short8)(*(const short8_a*)p);
            }

        float m_i[2][4], l_i[2][4];
        f32x4 o_acc[2][8];
#pragma unroll
        for (int i = 0; i < 2; i++) {
#pragma unroll
            for (int r = 0; r < 4; r++) { m_i[i][r] = -1e30f; l_i[i][r] = 0.f; }
#pragma unroll
            for (int jd = 0; jd < 8; jd++) o_acc[i][jd] = (f32x4){0.f, 0.f, 0.f, 0.f};
        }

        const int ktiles = 2 * qt + 2;   // causal: keys up to qt*128+127

        u32x4_a kr[4], vr[4];            // register prefetch of next K/V tile
        auto preload = [&](int kt2) {
            const int kk0 = kt2 * 64;
#pragma unroll
            for (int rep = 0; rep < 4; ++rep) {
                const int idx  = tid + rep * 256;
                const int krow = idx >> 4;
                const int dg   = (idx & 15) * 8;
                const size_t rb = (size_t)(b * Tn + kk0 + krow) * (2 * Cn) + h * HDn + dg;
                kr[rep] = *(const u32x4_a*)(kv + rb);
                vr[rep] = *(const u32x4_a*)(kv + rb + Cn);
            }
        };
        preload(0);

        for (int kt2 = 0; kt2 < ktiles; ++kt2) {
            const int kk0 = kt2 * 64;
            __syncthreads();   // LDS free from previous iter / previous half
            // stage K natural (b128), V transposed + XOR-swizzled (scalar b16)
#pragma unroll
            for (int rep = 0; rep < 4; ++rep) {
                const int idx  = tid + rep * 256;
                const int krow = idx >> 4;
                const int l    = idx & 15;         // = d>>3 of this lane's 8 V elems
                const int dg   = l * 8;
                *(u32x4_a*)&Ks[krow * 136 + dg] = kr[rep];
                const int pcol = krow ^ ((l & 7) << 3);
                const unsigned short* ve = (const unsigned short*)&vr[rep];
#pragma unroll
                for (int e = 0; e < 8; e++) Vs[(dg + e) * 72 + pcol] = ve[e];
            }
            __syncthreads();
            if (kt2 + 1 < ktiles) preload(kt2 + 1);   // overlap HBM latency w/ compute

            // S = Q K^T  (wave: 32 q-rows x 64 keys, 2x4 tiles, 4 k-steps over HD=128)
            f32x4 s[2][4];
#pragma unroll
            for (int i = 0; i < 2; i++)
#pragma unroll
                for (int j = 0; j < 4; j++) s[i][j] = (f32x4){0.f, 0.f, 0.f, 0.f};
#pragma unroll
            for (int kk = 0; kk < 4; ++kk) {
                short8 kf[4];
#pragma unroll
                for (int j = 0; j < 4; j++)
                    kf[j] = (short8)(*(const short8_a*)&Ks[(j * 16 + l15) * 136 + kk * 32 + quad * 8]);
#pragma unroll
                for (int i = 0; i < 2; i++)
#pragma unroll
                    for (int j = 0; j < 4; j++)
                        s[i][j] = __builtin_amdgcn_mfma_f32_16x16x32_bf16(qf[i][kk], kf[j], s[i][j], 0, 0, 0);
            }

            // online softmax: row = i*16+quad*4+r, col = j*16+l15
            const bool needmask = (kk0 + 63 > qrow0);  // wave-uniform
#pragma unroll
            for (int i = 0; i < 2; i++) {
#pragma unroll
                for (int r = 0; r < 4; r++) {
                    const int qidx = qrow0 + i * 16 + quad * 4 + r;
                    float mx = -1e30f;
#pragma unroll
                    for (int j = 0; j < 4; j++) {
                        float v = s[i][j][r] * 0.08838834764831845f;
                        if (needmask) {
                            const int kidx = kk0 + j * 16 + l15;
                            v = (kidx <= qidx) ? v : -1e30f;
                        }
                        s[i][j][r] = v;
                        mx = fmaxf(mx, v);
                    }
#pragma unroll
                    for (int off = 1; off < 16; off <<= 1)
                        mx = fmaxf(mx, __shfl_xor(mx, off));
                    const float mn = fmaxf(m_i[i][r], mx);
                    const float al = __expf(fminf(m_i[i][r] - mn, 0.f));
                    m_i[i][r] = mn;
                    float rs = 0.f;
#pragma unroll
                    for (int j = 0; j < 4; j++) {
                        const float p = __expf(fminf(s[i][j][r] - mn, 0.f));
                        s[i][j][r] = p;
                        rs += p;
                    }
#pragma unroll
                    for (int off = 1; off < 16; off <<= 1)
                        rs += __shfl_xor(rs, off);
                    l_i[i][r] = l_i[i][r] * al + rs;
#pragma unroll
                    for (int jd = 0; jd < 8; jd++) o_acc[i][jd][r] *= al;
                    // P -> LDS (C-layout write; read back below in A-layout)
#pragma unroll
                    for (int j = 0; j < 4; j++)
                        Ps[wave][(i * 16 + quad * 4 + r) * 72 + j * 16 + l15] = f2b(s[i][j][r]);
                }
            }
            // Ps region is per-wave: drain this wave's LDS writes, no block barrier
            asm volatile("s_waitcnt lgkmcnt(0)" ::: "memory");

            // O += P V   (P: A-frag from Ps; V: B-frag from swizzled Vs)
#pragma unroll
            for (int kk2 = 0; kk2 < 2; ++kk2) {
                short8 pf[2];
#pragma unroll
                for (int i = 0; i < 2; i++)
                    pf[i] = (short8)(*(const short8_a*)&Ps[wave][(i * 16 + l15) * 72 + kk2 * 32 + quad * 8]);
#pragma unroll
                for (int jd = 0; jd < 8; jd++) {
                    const int d = jd * 16 + l15;
                    const int g = (d >> 3) & 7;
                    const int colb = ((4 * kk2 + quad) ^ g) * 8;
                    short8 vf = (short8)(*(const short8_a*)&Vs[d * 72 + colb]);
#pragma unroll
                    for (int i = 0; i < 2; i++)
                        o_acc[i][jd] = __builtin_amdgcn_mfma_f32_16x16x32_bf16(pf[i], vf, o_acc[i][jd], 0, 0, 0);
                }
            }
        }

        // epilogue: out[b*T + t, h*128 + d] = o/l  (overwrites this block's own q — safe)
#pragma unroll
        for (int i = 0; i < 2; i++) {
#pragma unroll
            for (int r = 0; r < 4; r++) {
                const float inv = 1.0f / fmaxf(l_i[i][r], 1e-20f);
                const int trow = qrow0 + i * 16 + quad * 4 + r;
#pragma unroll
                for (int jd = 0; jd < 8; jd++) {
                    const int col = h * HDn + jd * 16 + l15;
                    outp[(size_t)(b * Tn + trow) * Cn + col] = f2b(o_acc[i][jd][r] * inv);
                }
            }
        }
    }
}

extern "C" void kernel_launch(void* const* d_in, const int* in_sizes, int n_in,
                              void* d_out, int out_size, void* d_ws, size_t ws_size,
                              hipStream_t stream)
{
    const float* x      = (const float*)d_in[0]; // [B,T,C]  fp32
    const float* w_attn = (const float*)d_in[1]; // [3C,C]   fp32
    const float* w_proj = (const float*)d_in[2]; // [C,C]    fp32
    const float* b_proj = (const float*)d_in[3]; // [C]      fp32
    float* out = (float*)d_out;                  // [B,T,C]  fp32 (32 MiB)

    // Buffer plan:
    //   qbuf  = d_ws   [4096,2048] bf16 (16 MiB) — q, then attn output (same-block overwrite)
    //   kvbuf = d_out  [4096,4096] bf16 (32 MiB) — k|v, dead before proj GEMM writes fp32 out
    unsigned short* qbuf  = (unsigned short*)d_ws;
    unsigned short* kvbuf = (unsigned short*)d_out;

    // q  = x @ w_attn[0:2048]^T    : M=4096, N=2048, K=2048 (fp32 in, bf16 out)
    gemm_kernel<0, 0, 0><<<dim3(32, 16), 256, 0, stream>>>(x, w_attn, nullptr, qbuf,
                                                           Bn * Tn, Cn, Cn);
    // kv = x @ w_attn[2048:6144]^T : M=4096, N=4096, K=2048 (fp32 in, bf16 out)
    gemm_kernel<0, 0, 0><<<dim3(32, 32), 256, 0, stream>>>(x, w_attn + (size_t)Cn * Cn, nullptr,
                                                           kvbuf, Bn * Tn, 2 * Cn, Cn);
    // flash attention: q/kv bf16 -> att bf16 (over q), balanced q-tile pairing
    attn_kernel<<<dim3(8, Bn * Hn), 256, 0, stream>>>(qbuf, kvbuf, qbuf);
    // out = att @ w_proj^T + b_proj : M=4096, N=2048, K=2048 (A bf16, B fp32, out fp32)
    gemm_kernel<1, 1, 1><<<dim3(32, 16), 256, 0, stream>>>(qbuf, w_proj, b_proj, out,
                                                           Bn * Tn, Cn, Cn);
}

// Round 5
// 499.465 us; speedup vs baseline: 1.3134x; 1.1037x over previous
//
#include <hip/hip_runtime.h>
#include <hip/hip_bf16.h>
#include <stdint.h>
#include <stddef.h>

// Problem constants
#define Bn  2
#define Tn  2048
#define Cn  2048
#define Hn  16
#define HDn 128

// may_alias vector types for memory access (TBAA-safe); plain short8 for MFMA args
typedef short short8   __attribute__((ext_vector_type(8)));
typedef short short8_a __attribute__((ext_vector_type(8), may_alias));
typedef unsigned int u32x4_a __attribute__((ext_vector_type(4), may_alias));
typedef unsigned short u16x4_a __attribute__((ext_vector_type(4), may_alias));
typedef unsigned short u16x8_a __attribute__((ext_vector_type(8), may_alias));
typedef float f32x4 __attribute__((ext_vector_type(4)));

// address-space-qualified void for global_load_lds
typedef __attribute__((address_space(1))) const void av1_t;
typedef __attribute__((address_space(3))) void av3_t;

__device__ inline unsigned short f2b(float f) {
    union { float f; unsigned u; } v; v.f = f;
    unsigned r = v.u + 0x7fffu + ((v.u >> 16) & 1u);   // RNE
    return (unsigned short)(r >> 16);
}
// 4x fp32 bits -> 4x bf16 (RNE), operating on raw words
__device__ inline u16x4_a cvt4_f32_bf16(u32x4_a v) {
    u16x4_a h;
#pragma unroll
    for (int e = 0; e < 4; e++) {
        unsigned u = v[e];
        unsigned r = u + 0x7fffu + ((u >> 16) & 1u);
        h[e] = (unsigned short)(r >> 16);
    }
    return h;
}

// ---------------- fp32 -> bf16 bulk convert (memory-bound) ----------------
__global__ __launch_bounds__(256)
void cvt_kernel(const float* __restrict__ src, unsigned short* __restrict__ dst, int n)
{
    const int i = (blockIdx.x * 256 + threadIdx.x) * 8;
    if (i >= n) return;
    u32x4_a a = *(const u32x4_a*)((const unsigned*)src + i);
    u32x4_a b = *(const u32x4_a*)((const unsigned*)src + i + 4);
    u16x8_a o;
    u16x4_a ha = cvt4_f32_bf16(a), hb = cvt4_f32_bf16(b);
#pragma unroll
    for (int e = 0; e < 4; e++) { o[e] = ha[e]; o[e + 4] = hb[e]; }
    *(u16x8_a*)(dst + i) = o;
}

// ---------------- pure-bf16 GEMM, m97-style global_load_lds staging ----------------
// C[m,n] = sum_k A[m,k]*B[n,k] (+bias[n]); A,B bf16 row-major; out fp32 or bf16.
// 128x128 tile, BK=32, 256 threads = 4 waves, each wave 64x64 (4x4 MFMA tiles).
// LDS tiles UNPADDED 128x32 (global_load_lds needs lane-contiguous layout).
template<int OUT_F32, int HAS_BIAS>
__global__ __launch_bounds__(256)
void gemm_bb_kernel(const unsigned short* __restrict__ A,
                    const unsigned short* __restrict__ Bm,
                    const float* __restrict__ bias, void* __restrict__ Cv,
                    int M, int N, int K)
{
    __shared__ __align__(16) unsigned short As[128 * 32];
    __shared__ __align__(16) unsigned short Bs[128 * 32];

    const int tid  = threadIdx.x;
    const int lane = tid & 63;
    const int wave = tid >> 6;
    const int quad = lane >> 4;
    const int l15  = lane & 15;
    const int tm = blockIdx.x * 128;
    const int tn = blockIdx.y * 128;
    const int wr = (wave >> 1) * 64;
    const int wc = (wave & 1) * 64;

    // staging map: rep r in {0,1}: rows (r*4+wave)*16 + lane/4, cols (lane&3)*8
    const int srow = lane >> 2;
    const int scol = (lane & 3) * 8;

    f32x4 acc[4][4];
#pragma unroll
    for (int i = 0; i < 4; i++)
#pragma unroll
        for (int j = 0; j < 4; j++) acc[i][j] = (f32x4){0.f, 0.f, 0.f, 0.f};

    const int ksteps = K >> 5;
    for (int kt = 0; kt < ksteps; ++kt) {
        const int k0 = kt << 5;
        // async global -> LDS (16 B/lane; dest = wave base + lane*16, lane-contiguous)
#pragma unroll
        for (int r = 0; r < 2; r++) {
            const int row = (r * 4 + wave) * 16 + srow;
            __builtin_amdgcn_global_load_lds(
                (av1_t*)(A + (size_t)(tm + row) * K + k0 + scol),
                (av3_t*)(&As[row * 32 + scol]), 16, 0, 0);
            __builtin_amdgcn_global_load_lds(
                (av1_t*)(Bm + (size_t)(tn + row) * K + k0 + scol),
                (av3_t*)(&Bs[row * 32 + scol]), 16, 0, 0);
        }
        asm volatile("s_waitcnt vmcnt(0)" ::: "memory");
        __syncthreads();

        short8 af[4], bf[4];
#pragma unroll
        for (int i = 0; i < 4; i++)
            af[i] = (short8)(*(const short8_a*)&As[(wr + i * 16 + l15) * 32 + quad * 8]);
#pragma unroll
        for (int j = 0; j < 4; j++)
            bf[j] = (short8)(*(const short8_a*)&Bs[(wc + j * 16 + l15) * 32 + quad * 8]);
#pragma unroll
        for (int i = 0; i < 4; i++)
#pragma unroll
            for (int j = 0; j < 4; j++)
                acc[i][j] = __builtin_amdgcn_mfma_f32_16x16x32_bf16(af[i], bf[j], acc[i][j], 0, 0, 0);
        __syncthreads();
    }

    // epilogue: D row = quad*4 + reg, col = lane&15 (verified C/D layout)
#pragma unroll
    for (int i = 0; i < 4; i++) {
        const int row = tm + wr + i * 16 + quad * 4;
#pragma unroll
        for (int j = 0; j < 4; j++) {
            const int col = tn + wc + j * 16 + l15;
            const float bv = HAS_BIAS ? bias[col] : 0.0f;
#pragma unroll
            for (int r = 0; r < 4; r++) {
                if (OUT_F32)
                    ((float*)Cv)[(size_t)(row + r) * N + col] = acc[i][j][r] + bv;
                else
                    ((unsigned short*)Cv)[(size_t)(row + r) * N + col] = f2b(acc[i][j][r] + bv);
            }
        }
    }
}

// ---------------- mixed fp32-input GEMM (fallback path, round-4 proven) ----------------
template<int A_BF16, int OUT_F32, int HAS_BIAS>
__global__ __launch_bounds__(256, 2)
void gemm_kernel(const void* __restrict__ Av, const float* __restrict__ Bf,
                 const float* __restrict__ bias, void* __restrict__ Cv,
                 int M, int N, int K)
{
    __shared__ __align__(16) unsigned short As[128 * 40];
    __shared__ __align__(16) unsigned short Bs[128 * 40];

    const int tid  = threadIdx.x;
    const int lane = tid & 63;
    const int wave = tid >> 6;
    const int quad = lane >> 4;
    const int l15  = lane & 15;
    const int tm = blockIdx.x * 128;
    const int tn = blockIdx.y * 128;
    const int wr = (wave >> 1) * 64;
    const int wc = (wave & 1) * 64;

    f32x4 acc[4][4];
#pragma unroll
    for (int i = 0; i < 4; i++)
#pragma unroll
        for (int j = 0; j < 4; j++) acc[i][j] = (f32x4){0.f, 0.f, 0.f, 0.f};

    u32x4_a apre[4], bpre[4];
    const int ksteps = K >> 5;
    const int r0 = tid >> 2;
    const int cg = (tid & 3) * 8;

    auto loadA = [&](int k0) {
        if (A_BF16) {
            const unsigned short* Ab = (const unsigned short*)Av;
            apre[0] = *(const u32x4_a*)(Ab + (size_t)(tm + r0) * K + k0 + cg);
            apre[1] = *(const u32x4_a*)(Ab + (size_t)(tm + r0 + 64) * K + k0 + cg);
        } else {
            const float* Af = (const float*)Av;
#pragma unroll
            for (int rep = 0; rep < 4; rep++) {
                const int idx = tid + rep * 256, row = idx >> 3, c4 = (idx & 7) * 4;
                apre[rep] = *(const u32x4_a*)(Af + (size_t)(tm + row) * K + k0 + c4);
            }
        }
    };
    auto loadB = [&](int k0) {
#pragma unroll
        for (int rep = 0; rep < 4; rep++) {
            const int idx = tid + rep * 256, row = idx >> 3, c4 = (idx & 7) * 4;
            bpre[rep] = *(const u32x4_a*)(Bf + (size_t)(tn + row) * K + k0 + c4);
        }
    };
    auto stage = [&]() {
        if (A_BF16) {
            *(u32x4_a*)&As[r0 * 40 + cg]        = apre[0];
            *(u32x4_a*)&As[(r0 + 64) * 40 + cg] = apre[1];
        } else {
#pragma unroll
            for (int rep = 0; rep < 4; rep++) {
                const int idx = tid + rep * 256, row = idx >> 3, c4 = (idx & 7) * 4;
                *(u16x4_a*)&As[row * 40 + c4] = cvt4_f32_bf16(apre[rep]);
            }
        }
#pragma unroll
        for (int rep = 0; rep < 4; rep++) {
            const int idx = tid + rep * 256, row = idx >> 3, c4 = (idx & 7) * 4;
            *(u16x4_a*)&Bs[row * 40 + c4] = cvt4_f32_bf16(bpre[rep]);
        }
    };

    loadA(0);
    loadB(0);

    for (int kt = 0; kt < ksteps; ++kt) {
        stage();
        __syncthreads();
        if (kt + 1 < ksteps) {
            const int k0 = (kt + 1) << 5;
            loadA(k0);
            loadB(k0);
        }
        short8 af[4], bf[4];
#pragma unroll
        for (int i = 0; i < 4; i++)
            af[i] = (short8)(*(const short8_a*)&As[(wr + i * 16 + l15) * 40 + quad * 8]);
#pragma unroll
        for (int j = 0; j < 4; j++)
            bf[j] = (short8)(*(const short8_a*)&Bs[(wc + j * 16 + l15) * 40 + quad * 8]);
#pragma unroll
        for (int i = 0; i < 4; i++)
#pragma unroll
            for (int j = 0; j < 4; j++)
                acc[i][j] = __builtin_amdgcn_mfma_f32_16x16x32_bf16(af[i], bf[j], acc[i][j], 0, 0, 0);
        __syncthreads();
    }

#pragma unroll
    for (int i = 0; i < 4; i++) {
        const int row = tm + wr + i * 16 + quad * 4;
#pragma unroll
        for (int j = 0; j < 4; j++) {
            const int col = tn + wc + j * 16 + l15;
            const float bv = HAS_BIAS ? bias[col] : 0.0f;
#pragma unroll
            for (int r = 0; r < 4; r++) {
                if (OUT_F32)
                    ((float*)Cv)[(size_t)(row + r) * N + col] = acc[i][j][r] + bv;
                else
                    ((unsigned short*)Cv)[(size_t)(row + r) * N + col] = f2b(acc[i][j][r] + bv);
            }
        }
    }
}

// ---------------- flash attention (round-4, balanced pairing + V swizzle) ----------------
__global__ __launch_bounds__(256, 1)
void attn_kernel(const unsigned short* __restrict__ q,
                 const unsigned short* __restrict__ kv,
                 unsigned short* __restrict__ outp)
{
    __shared__ __align__(16) unsigned short Ks[64 * 136];   // [key][d], stride 136
    __shared__ __align__(16) unsigned short Vs[128 * 72];   // [d][pcol] swizzled, stride 72
    __shared__ __align__(16) unsigned short Ps[4][32 * 72]; // per-wave P, stride 72

    const int qp   = blockIdx.x;          // q pair index (0..7)
    const int bh   = blockIdx.y;          // b*H + h (32)
    const int b    = bh >> 4;
    const int h    = bh & 15;
    const int tid  = threadIdx.x;
    const int lane = tid & 63;
    const int wave = tid >> 6;
    const int quad = lane >> 4;
    const int l15  = lane & 15;

    for (int half = 0; half < 2; ++half) {
        const int qt = half ? (15 - qp) : qp;
        const int qrow0 = qt * 128 + wave * 32;

        short8 qf[2][4];
#pragma unroll
        for (int i = 0; i < 2; i++)
#pragma unroll
            for (int kk = 0; kk < 4; kk++) {
                const unsigned short* p = q + (size_t)(b * Tn + qrow0 + i * 16 + l15) * Cn
                                          + h * HDn + kk * 32 + quad * 8;
                qf[i][kk] = (short8)(*(const short8_a*)p);
            }

        float m_i[2][4], l_i[2][4];
        f32x4 o_acc[2][8];
#pragma unroll
        for (int i = 0; i < 2; i++) {
#pragma unroll
            for (int r = 0; r < 4; r++) { m_i[i][r] = -1e30f; l_i[i][r] = 0.f; }
#pragma unroll
            for (int jd = 0; jd < 8; jd++) o_acc[i][jd] = (f32x4){0.f, 0.f, 0.f, 0.f};
        }

        const int ktiles = 2 * qt + 2;

        u32x4_a kr[4], vr[4];
        auto preload = [&](int kt2) {
            const int kk0 = kt2 * 64;
#pragma unroll
            for (int rep = 0; rep < 4; ++rep) {
                const int idx  = tid + rep * 256;
                const int krow = idx >> 4;
                const int dg   = (idx & 15) * 8;
                const size_t rb = (size_t)(b * Tn + kk0 + krow) * (2 * Cn) + h * HDn + dg;
                kr[rep] = *(const u32x4_a*)(kv + rb);
                vr[rep] = *(const u32x4_a*)(kv + rb + Cn);
            }
        };
        preload(0);

        for (int kt2 = 0; kt2 < ktiles; ++kt2) {
            const int kk0 = kt2 * 64;
            __syncthreads();
#pragma unroll
            for (int rep = 0; rep < 4; ++rep) {
                const int idx  = tid + rep * 256;
                const int krow = idx >> 4;
                const int l    = idx & 15;
                const int dg   = l * 8;
                *(u32x4_a*)&Ks[krow * 136 + dg] = kr[rep];
                const int pcol = krow ^ ((l & 7) << 3);
                const unsigned short* ve = (const unsigned short*)&vr[rep];
#pragma unroll
                for (int e = 0; e < 8; e++) Vs[(dg + e) * 72 + pcol] = ve[e];
            }
            __syncthreads();
            if (kt2 + 1 < ktiles) preload(kt2 + 1);

            f32x4 s[2][4];
#pragma unroll
            for (int i = 0; i < 2; i++)
#pragma unroll
                for (int j = 0; j < 4; j++) s[i][j] = (f32x4){0.f, 0.f, 0.f, 0.f};
#pragma unroll
            for (int kk = 0; kk < 4; ++kk) {
                short8 kf[4];
#pragma unroll
                for (int j = 0; j < 4; j++)
                    kf[j] = (short8)(*(const short8_a*)&Ks[(j * 16 + l15) * 136 + kk * 32 + quad * 8]);
#pragma unroll
                for (int i = 0; i < 2; i++)
#pragma unroll
                    for (int j = 0; j < 4; j++)
                        s[i][j] = __builtin_amdgcn_mfma_f32_16x16x32_bf16(qf[i][kk], kf[j], s[i][j], 0, 0, 0);
            }

            const bool needmask = (kk0 + 63 > qrow0);
#pragma unroll
            for (int i = 0; i < 2; i++) {
#pragma unroll
                for (int r = 0; r < 4; r++) {
                    const int qidx = qrow0 + i * 16 + quad * 4 + r;
                    float mx = -1e30f;
#pragma unroll
                    for (int j = 0; j < 4; j++) {
                        float v = s[i][j][r] * 0.08838834764831845f;
                        if (needmask) {
                            const int kidx = kk0 + j * 16 + l15;
                            v = (kidx <= qidx) ? v : -1e30f;
                        }
                        s[i][j][r] = v;
                        mx = fmaxf(mx, v);
                    }
#pragma unroll
                    for (int off = 1; off < 16; off <<= 1)
                        mx = fmaxf(mx, __shfl_xor(mx, off));
                    const float mn = fmaxf(m_i[i][r], mx);
                    const float al = __expf(fminf(m_i[i][r] - mn, 0.f));
                    m_i[i][r] = mn;
                    float rs = 0.f;
#pragma unroll
                    for (int j = 0; j < 4; j++) {
                        const float p = __expf(fminf(s[i][j][r] - mn, 0.f));
                        s[i][j][r] = p;
                        rs += p;
                    }
#pragma unroll
                    for (int off = 1; off < 16; off <<= 1)
                        rs += __shfl_xor(rs, off);
                    l_i[i][r] = l_i[i][r] * al + rs;
#pragma unroll
                    for (int jd = 0; jd < 8; jd++) o_acc[i][jd][r] *= al;
#pragma unroll
                    for (int j = 0; j < 4; j++)
                        Ps[wave][(i * 16 + quad * 4 + r) * 72 + j * 16 + l15] = f2b(s[i][j][r]);
                }
            }
            asm volatile("s_waitcnt lgkmcnt(0)" ::: "memory");

#pragma unroll
            for (int kk2 = 0; kk2 < 2; ++kk2) {
                short8 pf[2];
#pragma unroll
                for (int i = 0; i < 2; i++)
                    pf[i] = (short8)(*(const short8_a*)&Ps[wave][(i * 16 + l15) * 72 + kk2 * 32 + quad * 8]);
#pragma unroll
                for (int jd = 0; jd < 8; jd++) {
                    const int d = jd * 16 + l15;
                    const int g = (d >> 3) & 7;
                    const int colb = ((4 * kk2 + quad) ^ g) * 8;
                    short8 vf = (short8)(*(const short8_a*)&Vs[d * 72 + colb]);
#pragma unroll
                    for (int i = 0; i < 2; i++)
                        o_acc[i][jd] = __builtin_amdgcn_mfma_f32_16x16x32_bf16(pf[i], vf, o_acc[i][jd], 0, 0, 0);
                }
            }
        }

#pragma unroll
        for (int i = 0; i < 2; i++) {
#pragma unroll
            for (int r = 0; r < 4; r++) {
                const float inv = 1.0f / fmaxf(l_i[i][r], 1e-20f);
                const int trow = qrow0 + i * 16 + quad * 4 + r;
#pragma unroll
                for (int jd = 0; jd < 8; jd++) {
                    const int col = h * HDn + jd * 16 + l15;
                    outp[(size_t)(b * Tn + trow) * Cn + col] = f2b(o_acc[i][jd][r] * inv);
                }
            }
        }
    }
}

extern "C" void kernel_launch(void* const* d_in, const int* in_sizes, int n_in,
                              void* d_out, int out_size, void* d_ws, size_t ws_size,
                              hipStream_t stream)
{
    const float* x      = (const float*)d_in[0]; // [B,T,C]  fp32
    const float* w_attn = (const float*)d_in[1]; // [3C,C]   fp32
    const float* w_proj = (const float*)d_in[2]; // [C,C]    fp32
    const float* b_proj = (const float*)d_in[3]; // [C]      fp32
    float* out = (float*)d_out;                  // [B,T,C]  fp32 (32 MiB)

    const size_t MiB = 1024 * 1024;
    unsigned short* kvbuf = (unsigned short*)d_out;   // [4096,4096] bf16 scratch in d_out

    if (ws_size >= 48 * MiB) {
        // FAST PATH: pre-convert to bf16, m97-style global_load_lds GEMMs.
        // ws layout: xb [0,16M) | qbuf [16M,32M) | wb [32M,48M)
        unsigned short* xb   = (unsigned short*)d_ws;
        unsigned short* qbuf = (unsigned short*)((char*)d_ws + 16 * MiB);
        unsigned short* wb   = (unsigned short*)((char*)d_ws + 32 * MiB);

        const int nx  = Bn * Tn * Cn;        // 8.4M
        const int nwq = Cn * Cn;             // 4.2M
        const int nwkv = 2 * Cn * Cn;        // 8.4M

        cvt_kernel<<<nx / 8 / 256, 256, 0, stream>>>(x, xb, nx);
        cvt_kernel<<<nwq / 8 / 256, 256, 0, stream>>>(w_attn, wb, nwq);
        gemm_bb_kernel<0, 0><<<dim3(32, 16), 256, 0, stream>>>(xb, wb, nullptr, qbuf,
                                                               Bn * Tn, Cn, Cn);
        cvt_kernel<<<nwkv / 8 / 256, 256, 0, stream>>>(w_attn + (size_t)Cn * Cn, wb, nwkv);
        gemm_bb_kernel<0, 0><<<dim3(32, 32), 256, 0, stream>>>(xb, wb, nullptr, kvbuf,
                                                               Bn * Tn, 2 * Cn, Cn);
        attn_kernel<<<dim3(8, Bn * Hn), 256, 0, stream>>>(qbuf, kvbuf, qbuf);
        cvt_kernel<<<nwq / 8 / 256, 256, 0, stream>>>(w_proj, wb, nwq);
        gemm_bb_kernel<1, 1><<<dim3(32, 16), 256, 0, stream>>>(qbuf, wb, b_proj, out,
                                                               Bn * Tn, Cn, Cn);
    } else {
        // FALLBACK (round-4 proven): convert-in-staging GEMMs, needs only 16 MiB ws.
        unsigned short* qbuf = (unsigned short*)d_ws;

        gemm_kernel<0, 0, 0><<<dim3(32, 16), 256, 0, stream>>>(x, w_attn, nullptr, qbuf,
                                                               Bn * Tn, Cn, Cn);
        gemm_kernel<0, 0, 0><<<dim3(32, 32), 256, 0, stream>>>(x, w_attn + (size_t)Cn * Cn,
                                                               nullptr, kvbuf, Bn * Tn, 2 * Cn, Cn);
        attn_kernel<<<dim3(8, Bn * Hn), 256, 0, stream>>>(qbuf, kvbuf, qbuf);
        gemm_kernel<1, 1, 1><<<dim3(32, 16), 256, 0, stream>>>(qbuf, w_proj, b_proj, out,
                                                               Bn * Tn, Cn, Cn);
    }
}

// Round 6
// 435.362 us; speedup vs baseline: 1.5067x; 1.1472x over previous
//
#include <hip/hip_runtime.h>
#include <hip/hip_bf16.h>
#include <stdint.h>
#include <stddef.h>

// Problem constants
#define Bn  2
#define Tn  2048
#define Cn  2048
#define Hn  16
#define HDn 128

// may_alias vector types for memory access (TBAA-safe); plain short8 for MFMA args
typedef short short8   __attribute__((ext_vector_type(8)));
typedef short short8_a __attribute__((ext_vector_type(8), may_alias));
typedef unsigned int u32x4_a __attribute__((ext_vector_type(4), may_alias));
typedef unsigned short u16x4_a __attribute__((ext_vector_type(4), may_alias));
typedef unsigned short u16x8_a __attribute__((ext_vector_type(8), may_alias));
typedef float f32x4 __attribute__((ext_vector_type(4)));

// address-space-qualified void for global_load_lds
typedef __attribute__((address_space(1))) const void av1_t;
typedef __attribute__((address_space(3))) void av3_t;

__device__ inline unsigned short f2b(float f) {
    union { float f; unsigned u; } v; v.f = f;
    unsigned r = v.u + 0x7fffu + ((v.u >> 16) & 1u);   // RNE
    return (unsigned short)(r >> 16);
}
// 4x fp32 bits -> 4x bf16 (RNE), operating on raw words
__device__ inline u16x4_a cvt4_f32_bf16(u32x4_a v) {
    u16x4_a h;
#pragma unroll
    for (int e = 0; e < 4; e++) {
        unsigned u = v[e];
        unsigned r = u + 0x7fffu + ((u >> 16) & 1u);
        h[e] = (unsigned short)(r >> 16);
    }
    return h;
}

// ---------------- fp32 -> bf16 bulk convert (memory-bound) ----------------
__global__ __launch_bounds__(256)
void cvt_kernel(const float* __restrict__ src, unsigned short* __restrict__ dst, int n)
{
    const int i = (blockIdx.x * 256 + threadIdx.x) * 8;
    if (i >= n) return;
    u32x4_a a = *(const u32x4_a*)((const unsigned*)src + i);
    u32x4_a b = *(const u32x4_a*)((const unsigned*)src + i + 4);
    u16x8_a o;
    u16x4_a ha = cvt4_f32_bf16(a), hb = cvt4_f32_bf16(b);
#pragma unroll
    for (int e = 0; e < 4; e++) { o[e] = ha[e]; o[e + 4] = hb[e]; }
    *(u16x8_a*)(dst + i) = o;
}

// ---------------- pure-bf16 GEMM, m97-style global_load_lds staging ----------------
template<int OUT_F32, int HAS_BIAS>
__global__ __launch_bounds__(256)
void gemm_bb_kernel(const unsigned short* __restrict__ A,
                    const unsigned short* __restrict__ Bm,
                    const float* __restrict__ bias, void* __restrict__ Cv,
                    int M, int N, int K)
{
    __shared__ __align__(16) unsigned short As[128 * 32];
    __shared__ __align__(16) unsigned short Bs[128 * 32];

    const int tid  = threadIdx.x;
    const int lane = tid & 63;
    const int wave = tid >> 6;
    const int quad = lane >> 4;
    const int l15  = lane & 15;
    const int tm = blockIdx.x * 128;
    const int tn = blockIdx.y * 128;
    const int wr = (wave >> 1) * 64;
    const int wc = (wave & 1) * 64;

    const int srow = lane >> 2;
    const int scol = (lane & 3) * 8;

    f32x4 acc[4][4];
#pragma unroll
    for (int i = 0; i < 4; i++)
#pragma unroll
        for (int j = 0; j < 4; j++) acc[i][j] = (f32x4){0.f, 0.f, 0.f, 0.f};

    const int ksteps = K >> 5;
    for (int kt = 0; kt < ksteps; ++kt) {
        const int k0 = kt << 5;
#pragma unroll
        for (int r = 0; r < 2; r++) {
            const int row = (r * 4 + wave) * 16 + srow;
            __builtin_amdgcn_global_load_lds(
                (av1_t*)(A + (size_t)(tm + row) * K + k0 + scol),
                (av3_t*)(&As[row * 32 + scol]), 16, 0, 0);
            __builtin_amdgcn_global_load_lds(
                (av1_t*)(Bm + (size_t)(tn + row) * K + k0 + scol),
                (av3_t*)(&Bs[row * 32 + scol]), 16, 0, 0);
        }
        asm volatile("s_waitcnt vmcnt(0)" ::: "memory");
        __syncthreads();

        short8 af[4], bf[4];
#pragma unroll
        for (int i = 0; i < 4; i++)
            af[i] = (short8)(*(const short8_a*)&As[(wr + i * 16 + l15) * 32 + quad * 8]);
#pragma unroll
        for (int j = 0; j < 4; j++)
            bf[j] = (short8)(*(const short8_a*)&Bs[(wc + j * 16 + l15) * 32 + quad * 8]);
#pragma unroll
        for (int i = 0; i < 4; i++)
#pragma unroll
            for (int j = 0; j < 4; j++)
                acc[i][j] = __builtin_amdgcn_mfma_f32_16x16x32_bf16(af[i], bf[j], acc[i][j], 0, 0, 0);
        __syncthreads();
    }

#pragma unroll
    for (int i = 0; i < 4; i++) {
        const int row = tm + wr + i * 16 + quad * 4;
#pragma unroll
        for (int j = 0; j < 4; j++) {
            const int col = tn + wc + j * 16 + l15;
            const float bv = HAS_BIAS ? bias[col] : 0.0f;
#pragma unroll
            for (int r = 0; r < 4; r++) {
                if (OUT_F32)
                    ((float*)Cv)[(size_t)(row + r) * N + col] = acc[i][j][r] + bv;
                else
                    ((unsigned short*)Cv)[(size_t)(row + r) * N + col] = f2b(acc[i][j][r] + bv);
            }
        }
    }
}

// ---------------- mixed fp32-input GEMM (fallback path) ----------------
template<int A_BF16, int OUT_F32, int HAS_BIAS>
__global__ __launch_bounds__(256, 2)
void gemm_kernel(const void* __restrict__ Av, const float* __restrict__ Bf,
                 const float* __restrict__ bias, void* __restrict__ Cv,
                 int M, int N, int K)
{
    __shared__ __align__(16) unsigned short As[128 * 40];
    __shared__ __align__(16) unsigned short Bs[128 * 40];

    const int tid  = threadIdx.x;
    const int lane = tid & 63;
    const int wave = tid >> 6;
    const int quad = lane >> 4;
    const int l15  = lane & 15;
    const int tm = blockIdx.x * 128;
    const int tn = blockIdx.y * 128;
    const int wr = (wave >> 1) * 64;
    const int wc = (wave & 1) * 64;

    f32x4 acc[4][4];
#pragma unroll
    for (int i = 0; i < 4; i++)
#pragma unroll
        for (int j = 0; j < 4; j++) acc[i][j] = (f32x4){0.f, 0.f, 0.f, 0.f};

    u32x4_a apre[4], bpre[4];
    const int ksteps = K >> 5;
    const int r0 = tid >> 2;
    const int cg = (tid & 3) * 8;

    auto loadA = [&](int k0) {
        if (A_BF16) {
            const unsigned short* Ab = (const unsigned short*)Av;
            apre[0] = *(const u32x4_a*)(Ab + (size_t)(tm + r0) * K + k0 + cg);
            apre[1] = *(const u32x4_a*)(Ab + (size_t)(tm + r0 + 64) * K + k0 + cg);
        } else {
            const float* Af = (const float*)Av;
#pragma unroll
            for (int rep = 0; rep < 4; rep++) {
                const int idx = tid + rep * 256, row = idx >> 3, c4 = (idx & 7) * 4;
                apre[rep] = *(const u32x4_a*)(Af + (size_t)(tm + row) * K + k0 + c4);
            }
        }
    };
    auto loadB = [&](int k0) {
#pragma unroll
        for (int rep = 0; rep < 4; rep++) {
            const int idx = tid + rep * 256, row = idx >> 3, c4 = (idx & 7) * 4;
            bpre[rep] = *(const u32x4_a*)(Bf + (size_t)(tn + row) * K + k0 + c4);
        }
    };
    auto stage = [&]() {
        if (A_BF16) {
            *(u32x4_a*)&As[r0 * 40 + cg]        = apre[0];
            *(u32x4_a*)&As[(r0 + 64) * 40 + cg] = apre[1];
        } else {
#pragma unroll
            for (int rep = 0; rep < 4; rep++) {
                const int idx = tid + rep * 256, row = idx >> 3, c4 = (idx & 7) * 4;
                *(u16x4_a*)&As[row * 40 + c4] = cvt4_f32_bf16(apre[rep]);
            }
        }
#pragma unroll
        for (int rep = 0; rep < 4; rep++) {
            const int idx = tid + rep * 256, row = idx >> 3, c4 = (idx & 7) * 4;
            *(u16x4_a*)&Bs[row * 40 + c4] = cvt4_f32_bf16(bpre[rep]);
        }
    };

    loadA(0);
    loadB(0);

    for (int kt = 0; kt < ksteps; ++kt) {
        stage();
        __syncthreads();
        if (kt + 1 < ksteps) {
            const int k0 = (kt + 1) << 5;
            loadA(k0);
            loadB(k0);
        }
        short8 af[4], bf[4];
#pragma unroll
        for (int i = 0; i < 4; i++)
            af[i] = (short8)(*(const short8_a*)&As[(wr + i * 16 + l15) * 40 + quad * 8]);
#pragma unroll
        for (int j = 0; j < 4; j++)
            bf[j] = (short8)(*(const short8_a*)&Bs[(wc + j * 16 + l15) * 40 + quad * 8]);
#pragma unroll
        for (int i = 0; i < 4; i++)
#pragma unroll
            for (int j = 0; j < 4; j++)
                acc[i][j] = __builtin_amdgcn_mfma_f32_16x16x32_bf16(af[i], bf[j], acc[i][j], 0, 0, 0);
        __syncthreads();
    }

#pragma unroll
    for (int i = 0; i < 4; i++) {
        const int row = tm + wr + i * 16 + quad * 4;
#pragma unroll
        for (int j = 0; j < 4; j++) {
            const int col = tn + wc + j * 16 + l15;
            const float bv = HAS_BIAS ? bias[col] : 0.0f;
#pragma unroll
            for (int r = 0; r < 4; r++) {
                if (OUT_F32)
                    ((float*)Cv)[(size_t)(row + r) * N + col] = acc[i][j][r] + bv;
                else
                    ((unsigned short*)Cv)[(size_t)(row + r) * N + col] = f2b(acc[i][j][r] + bv);
            }
        }
    }
}

// ---------------- flash attention: 512 threads, 8 waves x 16 Q-rows ----------------
// Balanced pairing (qp, 15-qp): 34 k-tile iters/block. Grid 8x32.
// 2 waves/SIMD so softmax VALU overlaps MFMA across waves.
// Row-sum via MFMA against all-ones B-fragment (no sum shuffles).
__global__ __launch_bounds__(512, 1)
void attn_kernel(const unsigned short* __restrict__ q,
                 const unsigned short* __restrict__ kv,
                 unsigned short* __restrict__ outp)
{
    __shared__ __align__(16) unsigned short Ks[64 * 136];   // [key][d], stride 136
    __shared__ __align__(16) unsigned short Vs[128 * 72];   // [d][pcol] swizzled, stride 72
    __shared__ __align__(16) unsigned short Ps[8][16 * 72]; // per-wave P, stride 72

    const int qp   = blockIdx.x;          // q pair index (0..7)
    const int bh   = blockIdx.y;          // b*H + h (32)
    const int b    = bh >> 4;
    const int h    = bh & 15;
    const int tid  = threadIdx.x;
    const int lane = tid & 63;
    const int wave = tid >> 6;            // 0..7
    const int quad = lane >> 4;
    const int l15  = lane & 15;

    short8 ones;
#pragma unroll
    for (int e = 0; e < 8; e++) ones[e] = (short)0x3F80;   // bf16 1.0

    for (int half = 0; half < 2; ++half) {
        const int qt = half ? (15 - qp) : qp;
        const int qrow0 = qt * 128 + wave * 16;

        // Q A-fragments: rows qrow0 + l15, A[m=l15][k=quad*8+j]
        short8 qf[4];
#pragma unroll
        for (int kk = 0; kk < 4; kk++) {
            const unsigned short* p = q + (size_t)(b * Tn + qrow0 + l15) * Cn
                                      + h * HDn + kk * 32 + quad * 8;
            qf[kk] = (short8)(*(const short8_a*)p);
        }

        float m_i[4], l_i[4];
        f32x4 o_acc[8];
#pragma unroll
        for (int r = 0; r < 4; r++) { m_i[r] = -1e30f; l_i[r] = 0.f; }
#pragma unroll
        for (int jd = 0; jd < 8; jd++) o_acc[jd] = (f32x4){0.f, 0.f, 0.f, 0.f};

        const int ktiles = 2 * qt + 2;

        u32x4_a kr[2], vr[2];
        auto preload = [&](int kt2) {
            const int kk0 = kt2 * 64;
#pragma unroll
            for (int rep = 0; rep < 2; ++rep) {
                const int idx  = tid + rep * 512;     // 0..1023
                const int krow = idx >> 4;
                const int dg   = (idx & 15) * 8;
                const size_t rb = (size_t)(b * Tn + kk0 + krow) * (2 * Cn) + h * HDn + dg;
                kr[rep] = *(const u32x4_a*)(kv + rb);
                vr[rep] = *(const u32x4_a*)(kv + rb + Cn);
            }
        };
        preload(0);

        for (int kt2 = 0; kt2 < ktiles; ++kt2) {
            const int kk0 = kt2 * 64;
            __syncthreads();
#pragma unroll
            for (int rep = 0; rep < 2; ++rep) {
                const int idx  = tid + rep * 512;
                const int krow = idx >> 4;
                const int l    = idx & 15;
                const int dg   = l * 8;
                *(u32x4_a*)&Ks[krow * 136 + dg] = kr[rep];
                const int pcol = krow ^ ((l & 7) << 3);
                const unsigned short* ve = (const unsigned short*)&vr[rep];
#pragma unroll
                for (int e = 0; e < 8; e++) Vs[(dg + e) * 72 + pcol] = ve[e];
            }
            __syncthreads();
            if (kt2 + 1 < ktiles) preload(kt2 + 1);

            // S = Q K^T : wave computes 16 q-rows x 64 keys (4 j-frags)
            f32x4 s[4];
#pragma unroll
            for (int j = 0; j < 4; j++) s[j] = (f32x4){0.f, 0.f, 0.f, 0.f};
#pragma unroll
            for (int kk = 0; kk < 4; ++kk) {
                short8 kf[4];
#pragma unroll
                for (int j = 0; j < 4; j++)
                    kf[j] = (short8)(*(const short8_a*)&Ks[(j * 16 + l15) * 136 + kk * 32 + quad * 8]);
#pragma unroll
                for (int j = 0; j < 4; j++)
                    s[j] = __builtin_amdgcn_mfma_f32_16x16x32_bf16(qf[kk], kf[j], s[j], 0, 0, 0);
            }

            // online softmax: row = quad*4+r, col = j*16+l15
            const bool needmask = (kk0 + 63 > qrow0);  // wave-uniform
            float alr[4];
#pragma unroll
            for (int r = 0; r < 4; r++) {
                const int qidx = qrow0 + quad * 4 + r;
                float mx = -1e30f;
#pragma unroll
                for (int j = 0; j < 4; j++) {
                    float v = s[j][r] * 0.08838834764831845f;
                    if (needmask) {
                        const int kidx = kk0 + j * 16 + l15;
                        v = (kidx <= qidx) ? v : -1e30f;
                    }
                    s[j][r] = v;
                    mx = fmaxf(mx, v);
                }
#pragma unroll
                for (int off = 1; off < 16; off <<= 1)
                    mx = fmaxf(mx, __shfl_xor(mx, off));
                const float mn = fmaxf(m_i[r], mx);
                alr[r] = __expf(fminf(m_i[r] - mn, 0.f));
                m_i[r] = mn;
#pragma unroll
                for (int j = 0; j < 4; j++) {
                    const float p = __expf(fminf(s[j][r] - mn, 0.f));
                    s[j][r] = p;
                }
#pragma unroll
                for (int jd = 0; jd < 8; jd++) o_acc[jd][r] *= alr[r];
#pragma unroll
                for (int j = 0; j < 4; j++)
                    Ps[wave][(quad * 4 + r) * 72 + j * 16 + l15] = f2b(s[j][r]);
            }
            // Ps region is per-wave: drain this wave's LDS writes, no block barrier
            asm volatile("s_waitcnt lgkmcnt(0)" ::: "memory");

            // O += P V ; row-sum via ones-MFMA (l-layout: every col = rowsum)
            f32x4 lacc = (f32x4){0.f, 0.f, 0.f, 0.f};
#pragma unroll
            for (int kk2 = 0; kk2 < 2; ++kk2) {
                short8 pf = (short8)(*(const short8_a*)&Ps[wave][l15 * 72 + kk2 * 32 + quad * 8]);
#pragma unroll
                for (int jd = 0; jd < 8; jd++) {
                    const int d = jd * 16 + l15;
                    const int g = (d >> 3) & 7;
                    const int colb = ((4 * kk2 + quad) ^ g) * 8;
                    short8 vf = (short8)(*(const short8_a*)&Vs[d * 72 + colb]);
                    o_acc[jd] = __builtin_amdgcn_mfma_f32_16x16x32_bf16(pf, vf, o_acc[jd], 0, 0, 0);
                }
                lacc = __builtin_amdgcn_mfma_f32_16x16x32_bf16(pf, ones, lacc, 0, 0, 0);
            }
#pragma unroll
            for (int r = 0; r < 4; r++)
                l_i[r] = l_i[r] * alr[r] + lacc[r];
        }

        // epilogue: out[b*T + t, h*128 + d] = o/l  (overwrites this block's own q — safe)
#pragma unroll
        for (int r = 0; r < 4; r++) {
            const float inv = 1.0f / fmaxf(l_i[r], 1e-20f);
            const int trow = qrow0 + quad * 4 + r;
#pragma unroll
            for (int jd = 0; jd < 8; jd++) {
                const int col = h * HDn + jd * 16 + l15;
                outp[(size_t)(b * Tn + trow) * Cn + col] = f2b(o_acc[jd][r] * inv);
            }
        }
    }
}

extern "C" void kernel_launch(void* const* d_in, const int* in_sizes, int n_in,
                              void* d_out, int out_size, void* d_ws, size_t ws_size,
                              hipStream_t stream)
{
    const float* x      = (const float*)d_in[0]; // [B,T,C]  fp32
    const float* w_attn = (const float*)d_in[1]; // [3C,C]   fp32
    const float* w_proj = (const float*)d_in[2]; // [C,C]    fp32
    const float* b_proj = (const float*)d_in[3]; // [C]      fp32
    float* out = (float*)d_out;                  // [B,T,C]  fp32 (32 MiB)

    const size_t MiB = 1024 * 1024;
    unsigned short* kvbuf = (unsigned short*)d_out;   // [4096,4096] bf16 scratch in d_out

    if (ws_size >= 48 * MiB) {
        // FAST PATH: pre-convert to bf16, m97-style global_load_lds GEMMs.
        // ws layout: xb [0,16M) | qbuf [16M,32M) | wb [32M,48M)
        unsigned short* xb   = (unsigned short*)d_ws;
        unsigned short* qbuf = (unsigned short*)((char*)d_ws + 16 * MiB);
        unsigned short* wb   = (unsigned short*)((char*)d_ws + 32 * MiB);

        const int nx  = Bn * Tn * Cn;        // 8.4M
        const int nwq = Cn * Cn;             // 4.2M
        const int nwkv = 2 * Cn * Cn;        // 8.4M

        cvt_kernel<<<nx / 8 / 256, 256, 0, stream>>>(x, xb, nx);
        cvt_kernel<<<nwq / 8 / 256, 256, 0, stream>>>(w_attn, wb, nwq);
        gemm_bb_kernel<0, 0><<<dim3(32, 16), 256, 0, stream>>>(xb, wb, nullptr, qbuf,
                                                               Bn * Tn, Cn, Cn);
        cvt_kernel<<<nwkv / 8 / 256, 256, 0, stream>>>(w_attn + (size_t)Cn * Cn, wb, nwkv);
        gemm_bb_kernel<0, 0><<<dim3(32, 32), 256, 0, stream>>>(xb, wb, nullptr, kvbuf,
                                                               Bn * Tn, 2 * Cn, Cn);
        attn_kernel<<<dim3(8, Bn * Hn), 512, 0, stream>>>(qbuf, kvbuf, qbuf);
        cvt_kernel<<<nwq / 8 / 256, 256, 0, stream>>>(w_proj, wb, nwq);
        gemm_bb_kernel<1, 1><<<dim3(32, 16), 256, 0, stream>>>(qbuf, wb, b_proj, out,
                                                               Bn * Tn, Cn, Cn);
    } else {
        // FALLBACK: convert-in-staging GEMMs, needs only 16 MiB ws.
        unsigned short* qbuf = (unsigned short*)d_ws;

        gemm_kernel<0, 0, 0><<<dim3(32, 16), 256, 0, stream>>>(x, w_attn, nullptr, qbuf,
                                                               Bn * Tn, Cn, Cn);
        gemm_kernel<0, 0, 0><<<dim3(32, 32), 256, 0, stream>>>(x, w_attn + (size_t)Cn * Cn,
                                                               nullptr, kvbuf, Bn * Tn, 2 * Cn, Cn);
        attn_kernel<<<dim3(8, Bn * Hn), 512, 0, stream>>>(qbuf, kvbuf, qbuf);
        gemm_kernel<1, 1, 1><<<dim3(32, 16), 256, 0, stream>>>(qbuf, w_proj, b_proj, out,
                                                               Bn * Tn, Cn, Cn);
    }
}

// Round 7
// 410.956 us; speedup vs baseline: 1.5962x; 1.0594x over previous
//
#include <hip/hip_runtime.h>
#include <hip/hip_bf16.h>
#include <stdint.h>
#include <stddef.h>

// Problem constants
#define Bn  2
#define Tn  2048
#define Cn  2048
#define Hn  16
#define HDn 128

// may_alias vector types for memory access (TBAA-safe); plain short8 for MFMA args
typedef short short8   __attribute__((ext_vector_type(8)));
typedef short short8_a __attribute__((ext_vector_type(8), may_alias));
typedef unsigned int u32x4_a __attribute__((ext_vector_type(4), may_alias));
typedef unsigned short u16x4_a __attribute__((ext_vector_type(4), may_alias));
typedef unsigned short u16x8_a __attribute__((ext_vector_type(8), may_alias));
typedef float f32x4 __attribute__((ext_vector_type(4)));

// address-space-qualified void for global_load_lds
typedef __attribute__((address_space(1))) const void av1_t;
typedef __attribute__((address_space(3))) void av3_t;

__device__ inline unsigned short f2b(float f) {
    union { float f; unsigned u; } v; v.f = f;
    unsigned r = v.u + 0x7fffu + ((v.u >> 16) & 1u);   // RNE
    return (unsigned short)(r >> 16);
}
__device__ inline u16x4_a cvt4_f32_bf16(u32x4_a v) {
    u16x4_a h;
#pragma unroll
    for (int e = 0; e < 4; e++) {
        unsigned u = v[e];
        unsigned r = u + 0x7fffu + ((u >> 16) & 1u);
        h[e] = (unsigned short)(r >> 16);
    }
    return h;
}

// ---------------- fp32 -> bf16 bulk convert (memory-bound) ----------------
__global__ __launch_bounds__(256)
void cvt_kernel(const float* __restrict__ src, unsigned short* __restrict__ dst, int n)
{
    const int i = (blockIdx.x * 256 + threadIdx.x) * 8;
    if (i >= n) return;
    u32x4_a a = *(const u32x4_a*)((const unsigned*)src + i);
    u32x4_a b = *(const u32x4_a*)((const unsigned*)src + i + 4);
    u16x8_a o;
    u16x4_a ha = cvt4_f32_bf16(a), hb = cvt4_f32_bf16(b);
#pragma unroll
    for (int e = 0; e < 4; e++) { o[e] = ha[e]; o[e + 4] = hb[e]; }
    *(u16x8_a*)(dst + i) = o;
}

// ---------------- pure-bf16 GEMM, m97-style global_load_lds staging ----------------
template<int OUT_F32, int HAS_BIAS>
__global__ __launch_bounds__(256)
void gemm_bb_kernel(const unsigned short* __restrict__ A,
                    const unsigned short* __restrict__ Bm,
                    const float* __restrict__ bias, void* __restrict__ Cv,
                    int M, int N, int K)
{
    __shared__ __align__(16) unsigned short As[128 * 32];
    __shared__ __align__(16) unsigned short Bs[128 * 32];

    const int tid  = threadIdx.x;
    const int lane = tid & 63;
    const int wave = tid >> 6;
    const int quad = lane >> 4;
    const int l15  = lane & 15;
    const int tm = blockIdx.x * 128;
    const int tn = blockIdx.y * 128;
    const int wr = (wave >> 1) * 64;
    const int wc = (wave & 1) * 64;

    const int srow = lane >> 2;
    const int scol = (lane & 3) * 8;

    f32x4 acc[4][4];
#pragma unroll
    for (int i = 0; i < 4; i++)
#pragma unroll
        for (int j = 0; j < 4; j++) acc[i][j] = (f32x4){0.f, 0.f, 0.f, 0.f};

    const int ksteps = K >> 5;
    for (int kt = 0; kt < ksteps; ++kt) {
        const int k0 = kt << 5;
#pragma unroll
        for (int r = 0; r < 2; r++) {
            const int row = (r * 4 + wave) * 16 + srow;
            __builtin_amdgcn_global_load_lds(
                (av1_t*)(A + (size_t)(tm + row) * K + k0 + scol),
                (av3_t*)(&As[row * 32 + scol]), 16, 0, 0);
            __builtin_amdgcn_global_load_lds(
                (av1_t*)(Bm + (size_t)(tn + row) * K + k0 + scol),
                (av3_t*)(&Bs[row * 32 + scol]), 16, 0, 0);
        }
        asm volatile("s_waitcnt vmcnt(0)" ::: "memory");
        __syncthreads();

        short8 af[4], bf[4];
#pragma unroll
        for (int i = 0; i < 4; i++)
            af[i] = (short8)(*(const short8_a*)&As[(wr + i * 16 + l15) * 32 + quad * 8]);
#pragma unroll
        for (int j = 0; j < 4; j++)
            bf[j] = (short8)(*(const short8_a*)&Bs[(wc + j * 16 + l15) * 32 + quad * 8]);
#pragma unroll
        for (int i = 0; i < 4; i++)
#pragma unroll
            for (int j = 0; j < 4; j++)
                acc[i][j] = __builtin_amdgcn_mfma_f32_16x16x32_bf16(af[i], bf[j], acc[i][j], 0, 0, 0);
        __syncthreads();
    }

#pragma unroll
    for (int i = 0; i < 4; i++) {
        const int row = tm + wr + i * 16 + quad * 4;
#pragma unroll
        for (int j = 0; j < 4; j++) {
            const int col = tn + wc + j * 16 + l15;
            const float bv = HAS_BIAS ? bias[col] : 0.0f;
#pragma unroll
            for (int r = 0; r < 4; r++) {
                if (OUT_F32)
                    ((float*)Cv)[(size_t)(row + r) * N + col] = acc[i][j][r] + bv;
                else
                    ((unsigned short*)Cv)[(size_t)(row + r) * N + col] = f2b(acc[i][j][r] + bv);
            }
        }
    }
}

// ---------------- fused qkv GEMM: N=6144, split output (q | kv) ----------------
// Bm = full w_attn bf16 [6144, 2048]. tn < 2048 -> qbuf [M,2048]; else kvbuf [M,4096].
__global__ __launch_bounds__(256)
void gemm_qkv_kernel(const unsigned short* __restrict__ A,
                     const unsigned short* __restrict__ Bm,
                     unsigned short* __restrict__ qout,
                     unsigned short* __restrict__ kvout, int K)
{
    __shared__ __align__(16) unsigned short As[128 * 32];
    __shared__ __align__(16) unsigned short Bs[128 * 32];

    const int tid  = threadIdx.x;
    const int lane = tid & 63;
    const int wave = tid >> 6;
    const int quad = lane >> 4;
    const int l15  = lane & 15;
    const int tm = blockIdx.x * 128;
    const int tn = blockIdx.y * 128;
    const int wr = (wave >> 1) * 64;
    const int wc = (wave & 1) * 64;

    const int srow = lane >> 2;
    const int scol = (lane & 3) * 8;

    f32x4 acc[4][4];
#pragma unroll
    for (int i = 0; i < 4; i++)
#pragma unroll
        for (int j = 0; j < 4; j++) acc[i][j] = (f32x4){0.f, 0.f, 0.f, 0.f};

    const int ksteps = K >> 5;
    for (int kt = 0; kt < ksteps; ++kt) {
        const int k0 = kt << 5;
#pragma unroll
        for (int r = 0; r < 2; r++) {
            const int row = (r * 4 + wave) * 16 + srow;
            __builtin_amdgcn_global_load_lds(
                (av1_t*)(A + (size_t)(tm + row) * K + k0 + scol),
                (av3_t*)(&As[row * 32 + scol]), 16, 0, 0);
            __builtin_amdgcn_global_load_lds(
                (av1_t*)(Bm + (size_t)(tn + row) * K + k0 + scol),
                (av3_t*)(&Bs[row * 32 + scol]), 16, 0, 0);
        }
        asm volatile("s_waitcnt vmcnt(0)" ::: "memory");
        __syncthreads();

        short8 af[4], bf[4];
#pragma unroll
        for (int i = 0; i < 4; i++)
            af[i] = (short8)(*(const short8_a*)&As[(wr + i * 16 + l15) * 32 + quad * 8]);
#pragma unroll
        for (int j = 0; j < 4; j++)
            bf[j] = (short8)(*(const short8_a*)&Bs[(wc + j * 16 + l15) * 32 + quad * 8]);
#pragma unroll
        for (int i = 0; i < 4; i++)
#pragma unroll
            for (int j = 0; j < 4; j++)
                acc[i][j] = __builtin_amdgcn_mfma_f32_16x16x32_bf16(af[i], bf[j], acc[i][j], 0, 0, 0);
        __syncthreads();
    }

    // block-uniform output select
    unsigned short* base = (tn < Cn) ? qout : kvout;
    const int cofs = (tn < Cn) ? 0 : Cn;
    const size_t ostr = (tn < Cn) ? Cn : 2 * Cn;
#pragma unroll
    for (int i = 0; i < 4; i++) {
        const int row = tm + wr + i * 16 + quad * 4;
#pragma unroll
        for (int j = 0; j < 4; j++) {
            const int col = tn + wc + j * 16 + l15 - cofs;
#pragma unroll
            for (int r = 0; r < 4; r++)
                base[(size_t)(row + r) * ostr + col] = f2b(acc[i][j][r]);
        }
    }
}

// ---------------- flash attention: 512 threads, 8 waves x 16 Q-rows, 128-key tiles ----
// Balanced pairing (qp, 15-qp): (qp+1) + (16-qp) = 17 k-tile iters/block. Grid 8x32.
// Row-sum via MFMA against all-ones B-fragment. LDS ~102 KB (of 160 KB).
__global__ __launch_bounds__(512, 2)
void attn_kernel(const unsigned short* __restrict__ q,
                 const unsigned short* __restrict__ kv,
                 unsigned short* __restrict__ outp)
{
    __shared__ __align__(16) unsigned short Ks[128 * 136];   // [key][d], stride 136
    __shared__ __align__(16) unsigned short Vs[128 * 136];   // [d][pcol] swizzled, stride 136
    __shared__ __align__(16) unsigned short Ps[8][16 * 136]; // per-wave P (16 rows x 128 keys)

    const int qp   = blockIdx.x;          // q pair index (0..7)
    const int bh   = blockIdx.y;          // b*H + h (32)
    const int b    = bh >> 4;
    const int h    = bh & 15;
    const int tid  = threadIdx.x;
    const int lane = tid & 63;
    const int wave = tid >> 6;            // 0..7
    const int quad = lane >> 4;
    const int l15  = lane & 15;

    short8 ones;
#pragma unroll
    for (int e = 0; e < 8; e++) ones[e] = (short)0x3F80;   // bf16 1.0

    for (int half = 0; half < 2; ++half) {
        const int qt = half ? (15 - qp) : qp;
        const int qrow0 = qt * 128 + wave * 16;

        // Q A-fragments: rows qrow0 + l15, A[m=l15][k=quad*8+j]
        short8 qf[4];
#pragma unroll
        for (int kk = 0; kk < 4; kk++) {
            const unsigned short* p = q + (size_t)(b * Tn + qrow0 + l15) * Cn
                                      + h * HDn + kk * 32 + quad * 8;
            qf[kk] = (short8)(*(const short8_a*)p);
        }

        float m_i[4], l_i[4];
        f32x4 o_acc[8];
#pragma unroll
        for (int r = 0; r < 4; r++) { m_i[r] = -1e30f; l_i[r] = 0.f; }
#pragma unroll
        for (int jd = 0; jd < 8; jd++) o_acc[jd] = (f32x4){0.f, 0.f, 0.f, 0.f};

        const int ktiles = qt + 1;   // 128-key tiles, causal

        u32x4_a kr[4], vr[4];
        auto preload = [&](int kt2) {
            const int kk0 = kt2 * 128;
#pragma unroll
            for (int rep = 0; rep < 4; ++rep) {
                const int idx  = tid + rep * 512;     // 0..2047
                const int krow = idx >> 4;            // 0..127
                const int dg   = (idx & 15) * 8;
                const size_t rb = (size_t)(b * Tn + kk0 + krow) * (2 * Cn) + h * HDn + dg;
                kr[rep] = *(const u32x4_a*)(kv + rb);
                vr[rep] = *(const u32x4_a*)(kv + rb + Cn);
            }
        };
        preload(0);

        for (int kt2 = 0; kt2 < ktiles; ++kt2) {
            const int kk0 = kt2 * 128;
            __syncthreads();
            // stage K natural (b128), V transposed + XOR-swizzled (scalar b16)
#pragma unroll
            for (int rep = 0; rep < 4; ++rep) {
                const int idx  = tid + rep * 512;
                const int krow = idx >> 4;
                const int l    = idx & 15;
                const int dg   = l * 8;
                *(u32x4_a*)&Ks[krow * 136 + dg] = kr[rep];
                const int pcol = krow ^ ((l & 7) << 3);
                const unsigned short* ve = (const unsigned short*)&vr[rep];
#pragma unroll
                for (int e = 0; e < 8; e++) Vs[(dg + e) * 136 + pcol] = ve[e];
            }
            __syncthreads();
            if (kt2 + 1 < ktiles) preload(kt2 + 1);

            // S = Q K^T : 16 q-rows x 128 keys (8 j-frags), 4 k-steps over HD=128
            f32x4 s[8];
#pragma unroll
            for (int j = 0; j < 8; j++) s[j] = (f32x4){0.f, 0.f, 0.f, 0.f};
#pragma unroll
            for (int kk = 0; kk < 4; ++kk) {
                short8 kf[8];
#pragma unroll
                for (int j = 0; j < 8; j++)
                    kf[j] = (short8)(*(const short8_a*)&Ks[(j * 16 + l15) * 136 + kk * 32 + quad * 8]);
#pragma unroll
                for (int j = 0; j < 8; j++)
                    s[j] = __builtin_amdgcn_mfma_f32_16x16x32_bf16(qf[kk], kf[j], s[j], 0, 0, 0);
            }

            // online softmax: row = quad*4+r, col = j*16+l15
            const bool needmask = (kk0 + 127 > qrow0);  // wave-uniform (diagonal tile only)
            float alr[4];
#pragma unroll
            for (int r = 0; r < 4; r++) {
                const int qidx = qrow0 + quad * 4 + r;
                float mx = -1e30f;
#pragma unroll
                for (int j = 0; j < 8; j++) {
                    float v = s[j][r] * 0.08838834764831845f;
                    if (needmask) {
                        const int kidx = kk0 + j * 16 + l15;
                        v = (kidx <= qidx) ? v : -1e30f;
                    }
                    s[j][r] = v;
                    mx = fmaxf(mx, v);
                }
#pragma unroll
                for (int off = 1; off < 16; off <<= 1)
                    mx = fmaxf(mx, __shfl_xor(mx, off));
                const float mn = fmaxf(m_i[r], mx);
                alr[r] = __expf(fminf(m_i[r] - mn, 0.f));
                m_i[r] = mn;
#pragma unroll
                for (int j = 0; j < 8; j++) {
                    const float p = __expf(fminf(s[j][r] - mn, 0.f));
                    s[j][r] = p;
                }
#pragma unroll
                for (int jd = 0; jd < 8; jd++) o_acc[jd][r] *= alr[r];
#pragma unroll
                for (int j = 0; j < 8; j++)
                    Ps[wave][(quad * 4 + r) * 136 + j * 16 + l15] = f2b(s[j][r]);
            }
            // Ps region is per-wave: drain this wave's LDS writes, no block barrier
            asm volatile("s_waitcnt lgkmcnt(0)" ::: "memory");

            // O += P V ; row-sum via ones-MFMA (l-layout: every col = rowsum)
            f32x4 lacc = (f32x4){0.f, 0.f, 0.f, 0.f};
#pragma unroll
            for (int kk2 = 0; kk2 < 4; ++kk2) {
                short8 pf = (short8)(*(const short8_a*)&Ps[wave][l15 * 136 + kk2 * 32 + quad * 8]);
#pragma unroll
                for (int jd = 0; jd < 8; jd++) {
                    const int d = jd * 16 + l15;
                    const int g = (d >> 3) & 7;
                    const int colb = ((4 * kk2 + quad) ^ g) * 8;
                    short8 vf = (short8)(*(const short8_a*)&Vs[d * 136 + colb]);
                    o_acc[jd] = __builtin_amdgcn_mfma_f32_16x16x32_bf16(pf, vf, o_acc[jd], 0, 0, 0);
                }
                lacc = __builtin_amdgcn_mfma_f32_16x16x32_bf16(pf, ones, lacc, 0, 0, 0);
            }
#pragma unroll
            for (int r = 0; r < 4; r++)
                l_i[r] = l_i[r] * alr[r] + lacc[r];
        }

        // epilogue: out[b*T + t, h*128 + d] = o/l  (overwrites this block's own q — safe)
#pragma unroll
        for (int r = 0; r < 4; r++) {
            const float inv = 1.0f / fmaxf(l_i[r], 1e-20f);
            const int trow = qrow0 + quad * 4 + r;
#pragma unroll
            for (int jd = 0; jd < 8; jd++) {
                const int col = h * HDn + jd * 16 + l15;
                outp[(size_t)(b * Tn + trow) * Cn + col] = f2b(o_acc[jd][r] * inv);
            }
        }
    }
}

extern "C" void kernel_launch(void* const* d_in, const int* in_sizes, int n_in,
                              void* d_out, int out_size, void* d_ws, size_t ws_size,
                              hipStream_t stream)
{
    const float* x      = (const float*)d_in[0]; // [B,T,C]  fp32
    const float* w_attn = (const float*)d_in[1]; // [3C,C]   fp32
    const float* w_proj = (const float*)d_in[2]; // [C,C]    fp32
    const float* b_proj = (const float*)d_in[3]; // [C]      fp32
    float* out = (float*)d_out;                  // [B,T,C]  fp32 (32 MiB)

    const size_t MiB = 1024 * 1024;
    unsigned short* kvbuf = (unsigned short*)d_out;   // [4096,4096] bf16 scratch in d_out

    const int nx   = Bn * Tn * Cn;         // 8.4M
    const int nwq  = Cn * Cn;              // 4.2M
    const int nwkv = 2 * Cn * Cn;          // 8.4M
    const int nw全 = 0; (void)nwq;

    if (ws_size >= 56 * MiB) {
        // FUSED PATH: xb [0,16M) | qbuf [16M,32M) | wb [32M,56M) holds full w_attn bf16
        unsigned short* xb   = (unsigned short*)d_ws;
        unsigned short* qbuf = (unsigned short*)((char*)d_ws + 16 * MiB);
        unsigned short* wb   = (unsigned short*)((char*)d_ws + 32 * MiB);
        const int nwa = 3 * Cn * Cn;       // 12.6M

        cvt_kernel<<<nx / 8 / 256, 256, 0, stream>>>(x, xb, nx);
        cvt_kernel<<<nwa / 8 / 256, 256, 0, stream>>>(w_attn, wb, nwa);
        gemm_qkv_kernel<<<dim3(32, 48), 256, 0, stream>>>(xb, wb, qbuf, kvbuf, Cn);
        attn_kernel<<<dim3(8, Bn * Hn), 512, 0, stream>>>(qbuf, kvbuf, qbuf);
        cvt_kernel<<<nwq / 8 / 256, 256, 0, stream>>>(w_proj, wb, nwq);
        gemm_bb_kernel<1, 1><<<dim3(32, 16), 256, 0, stream>>>(qbuf, wb, b_proj, out,
                                                               Bn * Tn, Cn, Cn);
    } else {
        // 48-MiB PATH (rounds 5-6 proven): xb | qbuf | wb(16M, chunked weights)
        unsigned short* xb   = (unsigned short*)d_ws;
        unsigned short* qbuf = (unsigned short*)((char*)d_ws + 16 * MiB);
        unsigned short* wb   = (unsigned short*)((char*)d_ws + 32 * MiB);

        cvt_kernel<<<nx / 8 / 256, 256, 0, stream>>>(x, xb, nx);
        cvt_kernel<<<nwq / 8 / 256, 256, 0, stream>>>(w_attn, wb, nwq);
        gemm_bb_kernel<0, 0><<<dim3(32, 16), 256, 0, stream>>>(xb, wb, nullptr, qbuf,
                                                               Bn * Tn, Cn, Cn);
        cvt_kernel<<<nwkv / 8 / 256, 256, 0, stream>>>(w_attn + (size_t)Cn * Cn, wb, nwkv);
        gemm_bb_kernel<0, 0><<<dim3(32, 32), 256, 0, stream>>>(xb, wb, nullptr, kvbuf,
                                                               Bn * Tn, 2 * Cn, Cn);
        attn_kernel<<<dim3(8, Bn * Hn), 512, 0, stream>>>(qbuf, kvbuf, qbuf);
        cvt_kernel<<<nwq / 8 / 256, 256, 0, stream>>>(w_proj, wb, nwq);
        gemm_bb_kernel<1, 1><<<dim3(32, 16), 256, 0, stream>>>(qbuf, wb, b_proj, out,
                                                               Bn * Tn, Cn, Cn);
    }
}